// Round 1
// baseline (3181.405 us; speedup 1.0000x reference)
//
#include <hip/hip_runtime.h>
#include <stdint.h>

typedef __attribute__((ext_vector_type(4))) int   i32x4;
typedef __attribute__((ext_vector_type(8))) short bf16x8;
typedef __attribute__((ext_vector_type(4))) float f32x4;

#define DEV static __device__ __forceinline__

constexpr int  kB = 128, kT = 512, kD = 512, kH = 512;
constexpr int  kGC = 2048;               // 4*H
constexpr int  ROWS = 32;                // batch rows per block
constexpr int  NG = 4;                   // batch groups
constexpr int  NJ = 32;                  // column-slice blocks per cluster
constexpr int  NTHREADS = 512;
constexpr size_t SLOT_ELEMS = (size_t)kB * kH;            // bf16 elems per ring slot (65536) -> 128 KB
constexpr size_t WIMG_ELEMS = (size_t)2 * NJ * 4 * 32 * 512; // 4,194,304 bf16
constexpr size_t WIMG_BYTES = WIMG_ELEMS * 2;             // 8 MB
constexpr int  RFULL = kT + 1;           // 513
constexpr uint32_t CANARY = 0x7F7F7F7Fu; // bf16 0x7F7F = 3.4e38; |h|<=1.0 can never produce it

DEV ushort f2bf(float f) {
  uint32_t u = __float_as_uint(f);
  u += 0x7fff + ((u >> 16) & 1);        // round-to-nearest-even
  return (ushort)(u >> 16);
}
DEV int pk2(float a, float b) { return (int)((uint32_t)f2bf(a) | ((uint32_t)f2bf(b) << 16)); }
DEV float sigf(float v)  { return 1.f / (1.f + __expf(-v)); }
DEV float tanhf_(float v){ return 1.f - 2.f / (__expf(2.f * v) + 1.f); }

DEV uint64_t ald64(const uint64_t* p) {
  return __hip_atomic_load(p, __ATOMIC_RELAXED, __HIP_MEMORY_SCOPE_AGENT);
}
DEV bool bad64(uint64_t v) {
  return ((uint32_t)v == CANARY) || ((uint32_t)(v >> 32) == CANARY);
}

// ---- prep: W (L,1024,2048) fp32 -> bf16 MFMA B-fragment image ----
// layout elem idx = ((((l*32+j)*4+G)*32+ks)*64+lane)*8+e
// value = W[l][k][c], k = ks*32 + (lane>>4)*8 + e, c = G*512 + j*16 + (lane&15)
__global__ void prep_w(const float* __restrict__ W, ushort* __restrict__ wimg) {
  uint32_t idx = blockIdx.x * 256u + threadIdx.x;
  int e = idx & 7, lane = (idx >> 3) & 63, ks = (idx >> 9) & 31;
  int G = (idx >> 14) & 3, j = (idx >> 16) & 31, l = (idx >> 21) & 1;
  int k = ks * 32 + ((lane >> 4) << 3) + e;
  int c = G * 512 + j * 16 + (lane & 15);
  wimg[idx] = f2bf(W[(size_t)l * 1024 * 2048 + (size_t)k * 2048 + c]);
}

// ---- prep: initial h (hiddens[l][0]) fp32 -> ring slot 0 bf16 ----
__global__ void prep_init(const float* __restrict__ hiddens, ushort* __restrict__ r0, ushort* __restrict__ r1) {
  uint32_t idx = blockIdx.x * 256u + threadIdx.x;   // 0 .. 2*65536-1
  int l = idx >> 16; uint32_t r = idx & 65535u;
  ushort v = f2bf(hiddens[(size_t)(l * 2 + 0) * 65536 + r]);
  (l ? r1 : r0)[r] = v;
}

// ======================= BIG path: canary dataflow sync =======================
// Ring slots are write-once (R = T+1). Rings are pre-filled with CANARY each
// launch; a slot dword != CANARY IS the readiness signal. No counters, no RMW,
// no vmcnt drain on the producer side. Consumers retry only missing 16B chunks.

struct Poll { uint64_t d[8]; };

DEV void poll_issue(Poll& P, const ushort* sb, int g, int tid) {
  #pragma unroll
  for (int p = 0; p < 4; ++p) {
    int o = (tid + p * NTHREADS) * 16, row = o >> 10, kb = o & 1023;
    const uint64_t* s = reinterpret_cast<const uint64_t*>(sb + (size_t)(g * ROWS + row) * kH + (kb >> 1));
    P.d[2 * p]     = ald64(s);
    P.d[2 * p + 1] = ald64(s + 1);
  }
}

template<int SLP>
DEV void poll_finish(Poll& P, const ushort* sb, ushort* Ab, int g, int tid) {
  #pragma unroll
  for (int p = 0; p < 4; ++p) {
    int o = (tid + p * NTHREADS) * 16, row = o >> 10, kb = o & 1023;
    const uint64_t* s = reinterpret_cast<const uint64_t*>(sb + (size_t)(g * ROWS + row) * kH + (kb >> 1));
    uint64_t lo = P.d[2 * p], hi = P.d[2 * p + 1];
    while (bad64(lo) || bad64(hi)) {
      __builtin_amdgcn_s_sleep(SLP);
      lo = ald64(s); hi = ald64(s + 1);
    }
    i32x4 v;
    v[0] = (int)(uint32_t)lo; v[1] = (int)(uint32_t)(lo >> 32);
    v[2] = (int)(uint32_t)hi; v[3] = (int)(uint32_t)(hi >> 32);
    *reinterpret_cast<i32x4*>(reinterpret_cast<char*>(Ab) + ((row * 1024 + kb) ^ ((row & 7) << 4))) = v;
  }
}

__launch_bounds__(NTHREADS, 2)
__global__ void lstm_big(const float* __restrict__ x, const float* __restrict__ hiddens,
                         const float* __restrict__ bias, const ushort* __restrict__ wimg,
                         ushort* __restrict__ ring0, ushort* __restrict__ ring1,
                         float* __restrict__ out) {
  __shared__ ushort AbufX[ROWS * 512];    // 32 KB: input half (k=0..511)
  __shared__ ushort AbufH[ROWS * 512];    // 32 KB: recurrent half (k=512..1023)
  __shared__ float  gbuf[4][ROWS][16];    // activated gates i,f,g,o

  const int tid  = threadIdx.x;
  const int lane = tid & 63;
  const int wv   = tid >> 6;
  const int G    = wv & 3;                // gate strip
  const int rf   = wv >> 2;               // row-fragment (16 rows)
  const int j    = blockIdx.x & 31;       // column slice
  const int g    = (blockIdx.x >> 5) & 3; // batch group
  const int l    = blockIdx.x >> 7;       // layer

  __threadfence();  // defensive: cross-replay cache hygiene (cheap, once)

  // W slice resident in registers: 32 ksteps x 16B B-fragments
  i32x4 wr[32];
  {
    const ushort* base = wimg + (((size_t)(l * NJ + j) * 4 + G) * 32) * 512 + lane * 8;
    #pragma unroll
    for (int ks = 0; ks < 32; ++ks)
      wr[ks] = *reinterpret_cast<const i32x4*>(base + ks * 512);
  }
  const float bval = bias[l * kGC + G * 512 + j * 16 + (lane & 15)];
  const int urow = tid >> 4, ucol = tid & 15;        // c/h-update role (fixed per thread)
  float creg = hiddens[((size_t)(l * 2 + 1) * kB + (g * ROWS + urow)) * kH + j * 16 + ucol];

  ushort* rrec = l ? ring1 : ring0;

  const int arow  = rf * 16 + (lane & 15);
  const int koff  = (lane >> 4) << 3;
  const int abase = arow * 1024;
  const int aswz  = (arow & 7) << 4;

  for (int t = 0; t < kT; ++t) {
    // ---------- stage both halves; polls overlap x-load/convert ----------
    Poll hp, xp;
    const ushort* hsrc = rrec + (size_t)t * SLOT_ELEMS;          // own h_{t-1} (slot t, write-once)
    poll_issue(hp, hsrc, g, tid);
    const ushort* xsrc = ring0 + (size_t)(t + 1) * SLOT_ELEMS;   // layer0 h_t (l==1 only)
    if (l == 1) {
      poll_issue(xp, xsrc, g, tid);
    } else {
      #pragma unroll
      for (int p = 0; p < 4; ++p) {
        int o = (tid + p * NTHREADS) * 16, row = o >> 10, kb = o & 1023;
        const float* src = x + ((size_t)(g * ROWS + row) * kT + t) * kD + (kb >> 1);
        f32x4 f0 = *reinterpret_cast<const f32x4*>(src);
        f32x4 f1 = *reinterpret_cast<const f32x4*>(src + 4);
        i32x4 v;
        v[0] = pk2(f0[0], f0[1]); v[1] = pk2(f0[2], f0[3]);
        v[2] = pk2(f1[0], f1[1]); v[3] = pk2(f1[2], f1[3]);
        *reinterpret_cast<i32x4*>(reinterpret_cast<char*>(AbufX) + ((row * 1024 + kb) ^ ((row & 7) << 4))) = v;
      }
    }
    poll_finish<1>(hp, hsrc, AbufH, g, tid);           // own-cluster: nearly always ready
    if (l == 1) poll_finish<4>(xp, xsrc, AbufX, g, tid); // cross-layer: larger backoff
    __syncthreads();                                   // S1: A tiles ready

    // ---------- full K=1024 MFMA ----------
    f32x4 acc = {};
    #pragma unroll
    for (int ks = 0; ks < 16; ++ks) {
      int off = (abase + ((ks * 32 + koff) << 1)) ^ aswz;
      i32x4 av = *reinterpret_cast<const i32x4*>(reinterpret_cast<const char*>(AbufX) + off);
      acc = __builtin_amdgcn_mfma_f32_16x16x32_bf16(
              *reinterpret_cast<bf16x8*>(&av), *reinterpret_cast<bf16x8*>(&wr[ks]), acc, 0, 0, 0);
    }
    #pragma unroll
    for (int ks = 0; ks < 16; ++ks) {
      int off = (abase + ((ks * 32 + koff) << 1)) ^ aswz;
      i32x4 av = *reinterpret_cast<const i32x4*>(reinterpret_cast<const char*>(AbufH) + off);
      acc = __builtin_amdgcn_mfma_f32_16x16x32_bf16(
              *reinterpret_cast<bf16x8*>(&av), *reinterpret_cast<bf16x8*>(&wr[16 + ks]), acc, 0, 0, 0);
    }

    // ---------- activation + gate exchange ----------
    #pragma unroll
    for (int q = 0; q < 4; ++q) {
      float v2 = acc[q] + bval;
      v2 = (G == 2) ? tanhf_(v2) : sigf(v2);
      gbuf[G][rf * 16 + ((lane >> 4) << 2) + q][lane & 15] = v2;  // C/D map: row=(lane>>4)*4+q, col=lane&15
    }
    __syncthreads();                                   // S2: gates ready

    // ---------- c/h update + immediate publish (c in register, shfl pack) ----------
    {
      float iv = gbuf[0][urow][ucol], fv = gbuf[1][urow][ucol];
      float gv = gbuf[2][urow][ucol], ov = gbuf[3][urow][ucol];
      creg = fv * creg + iv * gv;
      float hh = ov * tanhf_(creg);
      int b = g * ROWS + urow;
      uint32_t me    = f2bf(hh);
      uint32_t other = (uint32_t)__shfl_xor((int)me, 1);  // partner col^1 (same wave)
      if (!(ucol & 1)) {
        uint32_t pkv = me | (other << 16);
        uint32_t* dst = (uint32_t*)(rrec + (size_t)(t + 1) * SLOT_ELEMS
                                    + (size_t)b * kH + j * 16 + ucol);
        __hip_atomic_store(dst, pkv, __ATOMIC_RELAXED, __HIP_MEMORY_SCOPE_AGENT);
      }
      if (l == 1) out[((size_t)b * kT + t) * kH + j * 16 + ucol] = hh;
      if (t == kT - 1) {
        size_t hb = (size_t)kB * kT * kH;
        out[hb + ((size_t)(l * 2 + 0) * kB + b) * kH + j * 16 + ucol] = hh;
        out[hb + ((size_t)(l * 2 + 1) * kB + b) * kH + j * 16 + ucol] = creg;
      }
    }
    // no barrier: next S1 protects gbuf reads vs next-step gbuf writes;
    // AbufX/H overwrites are fenced by S2 (all compute reads precede S2).
  }
}

// ======================= small-workspace fallback (unchanged) =======================

template<bool BIG>
DEV void stage_ring(ushort* Abuf_, const ushort* rbase, int g, int tid) {
  #pragma unroll
  for (int p = 0; p < 4; ++p) {
    int o = (tid + p * NTHREADS) * 16;       // dest byte offset in 32KB half-tile
    int row = o >> 10, kb = o & 1023;
    const ushort* src = rbase + (size_t)(g * ROWS + row) * kH + (kb >> 1);
    i32x4 v;
    if (BIG) {
      v = *reinterpret_cast<const i32x4*>(src);
    } else {
      uint64_t lo = __hip_atomic_load((const uint64_t*)src,       __ATOMIC_RELAXED, __HIP_MEMORY_SCOPE_AGENT);
      uint64_t hi = __hip_atomic_load((const uint64_t*)(src + 4), __ATOMIC_RELAXED, __HIP_MEMORY_SCOPE_AGENT);
      v[0] = (int)(uint32_t)lo; v[1] = (int)(uint32_t)(lo >> 32);
      v[2] = (int)(uint32_t)hi; v[3] = (int)(uint32_t)(hi >> 32);
    }
    *reinterpret_cast<i32x4*>(reinterpret_cast<char*>(Abuf_) + ((row * 1024 + kb) ^ ((row & 7) << 4))) = v;
  }
}

template<bool BIG>
__launch_bounds__(NTHREADS, 2)
__global__ void lstm_main(const float* __restrict__ x, const float* __restrict__ hiddens,
                          const float* __restrict__ bias, const ushort* __restrict__ wimg,
                          ushort* __restrict__ ring0, ushort* __restrict__ ring1,
                          int* __restrict__ cnt, int* __restrict__ cons0,
                          float* __restrict__ out, int R0, int R1) {
  __shared__ ushort Abuf[ROWS * 512];     // 32 KB: one K-half, byte-XOR swizzled
  __shared__ float  gbuf[4][ROWS][16];    // activated gates i,f,g,o
  __shared__ float  cbuf[ROWS][16];       // cell state (fp32, block-resident)
  __shared__ float  hbuf[ROWS][16];

  const int tid  = threadIdx.x;
  const int lane = tid & 63;
  const int wv   = tid >> 6;
  const int G    = wv & 3;                // gate strip
  const int rf   = wv >> 2;               // row-fragment (16 rows)
  const int j    = blockIdx.x & 31;       // column slice
  const int g    = (blockIdx.x >> 5) & 3; // batch group
  const int l    = blockIdx.x >> 7;       // layer

  __threadfence();  // entry agent fence: kill cross-replay stale cache lines

  i32x4 wr[32];
  {
    const ushort* base = wimg + (((size_t)(l * NJ + j) * 4 + G) * 32) * 512 + lane * 8;
    #pragma unroll
    for (int ks = 0; ks < 32; ++ks)
      wr[ks] = *reinterpret_cast<const i32x4*>(base + ks * 512);
  }
  const float bval = bias[l * kGC + G * 512 + j * 16 + (lane & 15)];
  {
    int row = tid >> 4, col = tid & 15;
    cbuf[row][col] = hiddens[((size_t)(l * 2 + 1) * kB + (g * ROWS + row)) * kH + j * 16 + col];
  }
  int* mycnt = cnt + (l * NG + g) * kT;
  int* c0cnt = cnt + g * kT;
  ushort* rrec = l ? ring1 : ring0;
  const int Rrec = l ? R1 : R0;

  const int arow  = rf * 16 + (lane & 15);
  const int koff  = (lane >> 4) << 3;
  const int abase = arow * 1024;
  const int aswz  = (arow & 7) << 4;

  __syncthreads();

  for (int t = 0; t < kT; ++t) {
    if (l == 1) {
      if (tid == 0) {
        while (__hip_atomic_load(&c0cnt[t], __ATOMIC_RELAXED, __HIP_MEMORY_SCOPE_AGENT) < NJ)
          __builtin_amdgcn_s_sleep(2);
      }
      __syncthreads();
      stage_ring<BIG>(Abuf, ring0 + (size_t)((t + 1) % R0) * SLOT_ELEMS, g, tid);
    } else {
      #pragma unroll
      for (int p = 0; p < 4; ++p) {
        int o = (tid + p * NTHREADS) * 16;
        int row = o >> 10, kb = o & 1023;
        const float* src = x + ((size_t)(g * ROWS + row) * kT + t) * kD + (kb >> 1);
        f32x4 f0 = *reinterpret_cast<const f32x4*>(src);
        f32x4 f1 = *reinterpret_cast<const f32x4*>(src + 4);
        i32x4 v;
        v[0] = pk2(f0[0], f0[1]); v[1] = pk2(f0[2], f0[3]);
        v[2] = pk2(f1[0], f1[1]); v[3] = pk2(f1[2], f1[3]);
        *reinterpret_cast<i32x4*>(reinterpret_cast<char*>(Abuf) + ((row * 1024 + kb) ^ ((row & 7) << 4))) = v;
      }
    }
    __syncthreads();
    if (!BIG && l == 1 && tid == 0)
      __hip_atomic_fetch_add(&cons0[g * kT + t], 1, __ATOMIC_RELAXED, __HIP_MEMORY_SCOPE_AGENT);

    f32x4 acc = {};
    #pragma unroll
    for (int ks = 0; ks < 16; ++ks) {
      int off = (abase + ((ks * 32 + koff) << 1)) ^ aswz;
      i32x4 av = *reinterpret_cast<const i32x4*>(reinterpret_cast<const char*>(Abuf) + off);
      acc = __builtin_amdgcn_mfma_f32_16x16x32_bf16(
              *reinterpret_cast<bf16x8*>(&av), *reinterpret_cast<bf16x8*>(&wr[ks]), acc, 0, 0, 0);
    }
    __syncthreads();

    if (t > 0) {
      if (tid == 0) {
        while (__hip_atomic_load(&mycnt[t - 1], __ATOMIC_RELAXED, __HIP_MEMORY_SCOPE_AGENT) < NJ)
          __builtin_amdgcn_s_sleep(2);
        if (!BIG && l == 0 && t >= R0) {
          while (__hip_atomic_load(&cons0[g * kT + (t - R0)], __ATOMIC_RELAXED, __HIP_MEMORY_SCOPE_AGENT) < NJ)
            __builtin_amdgcn_s_sleep(2);
        }
      }
      __syncthreads();
    }
    stage_ring<BIG>(Abuf, rrec + (size_t)(t % Rrec) * SLOT_ELEMS, g, tid);
    __syncthreads();

    #pragma unroll
    for (int ks = 0; ks < 16; ++ks) {
      int off = (abase + ((ks * 32 + koff) << 1)) ^ aswz;
      i32x4 av = *reinterpret_cast<const i32x4*>(reinterpret_cast<const char*>(Abuf) + off);
      acc = __builtin_amdgcn_mfma_f32_16x16x32_bf16(
              *reinterpret_cast<bf16x8*>(&av), *reinterpret_cast<bf16x8*>(&wr[16 + ks]), acc, 0, 0, 0);
    }

    #pragma unroll
    for (int q = 0; q < 4; ++q) {
      float v2 = acc[q] + bval;
      v2 = (G == 2) ? tanhf_(v2) : sigf(v2);
      gbuf[G][rf * 16 + ((lane >> 4) << 2) + q][lane & 15] = v2;
    }
    __syncthreads();

    {
      int row = tid >> 4, col = tid & 15;
      float iv = gbuf[0][row][col], fv = gbuf[1][row][col];
      float gv = gbuf[2][row][col], ov = gbuf[3][row][col];
      float cc = fv * cbuf[row][col] + iv * gv;
      cbuf[row][col] = cc;
      float hh = ov * tanhf_(cc);
      hbuf[row][col] = hh;
      int b = g * ROWS + row;
      if (l == 1) out[((size_t)b * kT + t) * kH + j * 16 + col] = hh;
      if (t == kT - 1) {
        size_t hb = (size_t)kB * kT * kH;
        out[hb + ((size_t)(l * 2 + 0) * kB + b) * kH + j * 16 + col] = hh;
        out[hb + ((size_t)(l * 2 + 1) * kB + b) * kH + j * 16 + col] = cc;
      }
    }
    __syncthreads();

    if (tid < 256) {
      int row = tid >> 3, cp = tid & 7;
      uint32_t pkv = (uint32_t)f2bf(hbuf[row][2 * cp]) | ((uint32_t)f2bf(hbuf[row][2 * cp + 1]) << 16);
      uint32_t* dst = (uint32_t*)(rrec + (size_t)((t + 1) % Rrec) * SLOT_ELEMS
                                  + (size_t)(g * ROWS + row) * kH + j * 16 + 2 * cp);
      __hip_atomic_store(dst, pkv, __ATOMIC_RELAXED, __HIP_MEMORY_SCOPE_AGENT);
    }
    asm volatile("s_waitcnt vmcnt(0)" ::: "memory");
    __syncthreads();
    if (tid == 0)
      __hip_atomic_fetch_add(&mycnt[t], 1, __ATOMIC_RELAXED, __HIP_MEMORY_SCOPE_AGENT);
  }
}

extern "C" void kernel_launch(void* const* d_in, const int* in_sizes, int n_in,
                              void* d_out, int out_size, void* d_ws, size_t ws_size,
                              hipStream_t stream) {
  const float* x  = (const float*)d_in[0];
  const float* hd = (const float*)d_in[1];
  const float* W  = (const float*)d_in[2];
  const float* b  = (const float*)d_in[3];
  float* out = (float*)d_out;

  char* ws = (char*)d_ws;
  ushort* wimg = (ushort*)ws;
  int* cnt  = (int*)(ws + WIMG_BYTES);             // 2*4*512 ints = 16 KB
  int* cons = (int*)(ws + WIMG_BYTES + 16384);     // 4*512 ints = 8 KB
  size_t ringoff = WIMG_BYTES + 32768;
  size_t avail = ws_size > ringoff ? ws_size - ringoff : 0;
  long rmax = (long)(avail / (2 * SLOT_ELEMS * 2));
  int R = (rmax >= RFULL) ? RFULL : (rmax >= 16 ? 16 : (rmax >= 2 ? (int)rmax : 2));
  ushort* ring0 = (ushort*)(ws + ringoff);
  ushort* ring1 = ring0 + (size_t)R * SLOT_ELEMS;

  if (R == RFULL) {
    // canary-fill both rings (write-once slots); prep_init overwrites slot 0 after
    hipMemsetAsync(ring0, 0x7F, (size_t)2 * RFULL * SLOT_ELEMS * 2, stream);
    prep_w<<<(int)(WIMG_ELEMS / 256), 256, 0, stream>>>(W, wimg);
    prep_init<<<(2 * kB * kH) / 256, 256, 0, stream>>>(hd, ring0, ring1);
    lstm_big<<<256, NTHREADS, 0, stream>>>(x, hd, b, wimg, ring0, ring1, out);
  } else {
    hipMemsetAsync(ws + WIMG_BYTES, 0, 32768, stream);
    prep_w<<<(int)(WIMG_ELEMS / 256), 256, 0, stream>>>(W, wimg);
    prep_init<<<(2 * kB * kH) / 256, 256, 0, stream>>>(hd, ring0, ring1);
    lstm_main<false><<<256, NTHREADS, 0, stream>>>(x, hd, b, wimg, ring0, ring1, cnt, cons, out, R, R);
  }
}